// Round 1
// baseline (369.582 us; speedup 1.0000x reference)
//
#include <hip/hip_runtime.h>

typedef _Float16 f16x8 __attribute__((ext_vector_type(8)));
typedef _Float16 f16x4 __attribute__((ext_vector_type(4)));
typedef float f32x4 __attribute__((ext_vector_type(4)));

// Async global->LDS, 16B per lane. LDS dest must be wave-uniform base; HW adds lane*16.
__device__ __forceinline__ void lds_load16(const _Float16* g, _Float16* l) {
    __builtin_amdgcn_global_load_lds(
        (const __attribute__((address_space(1))) void*)g,
        (__attribute__((address_space(3))) void*)l,
        16, 0, 0);
}

// ---------------------------------------------------------------------------
// NT GEMM: C[M,N] = alpha * A[M,K] * B[N,K]^T (+ bias), f16 inputs, fp32 acc.
// 128x128 block tile, BK=32, 256 threads (4 waves, 2x2 of 64x64 per wave),
// mfma_f32_16x16x32_f16, m97-style single-buffer global_load_lds staging.
// BIAS_MODE: 0 none, 1 bias[n] (per output col), 2 bias[m] (per output row).
// ---------------------------------------------------------------------------
template <int BIAS_MODE, bool OUT_F32>
__global__ __launch_bounds__(256, 2)
void gemm_nt_f16(const _Float16* __restrict__ A, const _Float16* __restrict__ B,
                 void* __restrict__ Cv, const float* __restrict__ bias,
                 int M, int N, int K, int lda, int ldb, int ldc,
                 long long strideA, long long strideB, long long strideC,
                 float alpha)
{
    const int z = blockIdx.z;
    A += (size_t)z * strideA;
    B += (size_t)z * strideB;

    const int m0 = blockIdx.y * 128;
    const int n0 = blockIdx.x * 128;

    __shared__ __align__(16) _Float16 As[128 * 32];
    __shared__ __align__(16) _Float16 Bs[128 * 32];

    const int t    = threadIdx.x;
    const int w    = t >> 6;      // wave 0..3
    const int lane = t & 63;
    const int ln   = lane & 15;
    const int kq   = lane >> 4;   // 0..3
    const int wm   = (w & 1) * 64;
    const int wn   = (w >> 1) * 64;

    // Staging: tile is 128 rows x 64B (32 halfs). 512 x 16B chunks, 2 per thread.
    // chunk i -> row i>>2, in-row half offset (i&3)*8. LDS dest = chunk*16B (contiguous).
    const int arow = t >> 2;          // 0..63
    const int kc   = (t & 3) * 8;     // half offset in row
    const _Float16* gA0 = A + (size_t)(m0 + arow) * lda + kc;
    const _Float16* gA1 = A + (size_t)(m0 + 64 + arow) * lda + kc;
    const _Float16* gB0 = B + (size_t)(n0 + arow) * ldb + kc;
    const _Float16* gB1 = B + (size_t)(n0 + 64 + arow) * ldb + kc;
    _Float16* lA0 = As + w * 512;          // wave-uniform bases
    _Float16* lA1 = As + 2048 + w * 512;
    _Float16* lB0 = Bs + w * 512;
    _Float16* lB1 = Bs + 2048 + w * 512;

    f32x4 acc[4][4] = {};

    for (int k0 = 0; k0 < K; k0 += 32) {
        __syncthreads();                 // previous tile fully consumed
        lds_load16(gA0 + k0, lA0);
        lds_load16(gA1 + k0, lA1);
        lds_load16(gB0 + k0, lB0);
        lds_load16(gB1 + k0, lB1);
        __syncthreads();                 // compiler emits vmcnt(0) drain before barrier

        f16x8 af[4], bf[4];
#pragma unroll
        for (int i = 0; i < 4; ++i)
            af[i] = *(const f16x8*)(As + (wm + i * 16 + ln) * 32 + kq * 8);
#pragma unroll
        for (int i = 0; i < 4; ++i)
            bf[i] = *(const f16x8*)(Bs + (wn + i * 16 + ln) * 32 + kq * 8);
#pragma unroll
        for (int i = 0; i < 4; ++i)
#pragma unroll
            for (int j = 0; j < 4; ++j)
                acc[i][j] = __builtin_amdgcn_mfma_f32_16x16x32_f16(af[i], bf[j], acc[i][j], 0, 0, 0);
    }

    // Epilogue. C/D layout: col = lane&15, row = (lane>>4)*4 + reg.
    float*     Cf = (float*)Cv;
    _Float16*  Ch = (_Float16*)Cv;
    const size_t cbase = (size_t)z * strideC;
#pragma unroll
    for (int i = 0; i < 4; ++i) {
        const int rbase = m0 + wm + i * 16 + kq * 4;
#pragma unroll
        for (int j = 0; j < 4; ++j) {
            const int gcol = n0 + wn + j * 16 + ln;
#pragma unroll
            for (int r = 0; r < 4; ++r) {
                float vv = acc[i][j][r] * alpha;
                if (BIAS_MODE == 1) vv += bias[gcol];
                if (BIAS_MODE == 2) vv += bias[rbase + r];
                const size_t idx = cbase + (size_t)(rbase + r) * ldc + gcol;
                if (OUT_F32) Cf[idx] = vv;
                else         Ch[idx] = (_Float16)vv;
            }
        }
    }
}

// ---------------------------------------------------------------------------
// f32 -> f16 convert, float4 per thread, exact grid (no tail).
// ---------------------------------------------------------------------------
__global__ __launch_bounds__(256)
void cvt_f32_f16(const float4* __restrict__ x, _Float16* __restrict__ y)
{
    const size_t i = (size_t)blockIdx.x * 256 + threadIdx.x;
    float4 f = x[i];
    f16x4 o = { (_Float16)f.x, (_Float16)f.y, (_Float16)f.z, (_Float16)f.w };
    *(f16x4*)(y + i * 4) = o;
}

// ---------------------------------------------------------------------------
// 1024x1024 f32 -> f16 transpose (W -> W^T) via padded LDS tile.
// ---------------------------------------------------------------------------
__global__ __launch_bounds__(256)
void transpose_w_1024(const float* __restrict__ W, _Float16* __restrict__ WT)
{
    __shared__ float tile[32][33];
    const int bx = blockIdx.x * 32;   // source col block
    const int by = blockIdx.y * 32;   // source row block
    const int tx = threadIdx.x;       // 0..31
    const int ty = threadIdx.y;       // 0..7
#pragma unroll
    for (int i = ty; i < 32; i += 8)
        tile[i][tx] = W[(size_t)(by + i) * 1024 + bx + tx];
    __syncthreads();
#pragma unroll
    for (int i = ty; i < 32; i += 8)
        WT[(size_t)(bx + i) * 1024 + by + tx] = (_Float16)tile[tx][i];
}

// ---------------------------------------------------------------------------
// Row softmax over 2048 f16 elements, in place. One 256-thread block per row,
// one f16x8 per thread, fp32 math.
// ---------------------------------------------------------------------------
__global__ __launch_bounds__(256)
void softmax_rows_2048(_Float16* __restrict__ S)
{
    const size_t row = blockIdx.x;
    _Float16* p = S + row * 2048;
    const int t = threadIdx.x, lane = t & 63, w = t >> 6;

    f16x8 v = *(const f16x8*)(p + t * 8);
    float x[8];
    float mx = -3.4e38f;
#pragma unroll
    for (int i = 0; i < 8; ++i) { x[i] = (float)v[i]; mx = fmaxf(mx, x[i]); }
#pragma unroll
    for (int off = 32; off > 0; off >>= 1) mx = fmaxf(mx, __shfl_xor(mx, off));

    __shared__ float rmax[4], rsum[4];
    if (lane == 0) rmax[w] = mx;
    __syncthreads();
    mx = fmaxf(fmaxf(rmax[0], rmax[1]), fmaxf(rmax[2], rmax[3]));

    float s = 0.f;
#pragma unroll
    for (int i = 0; i < 8; ++i) { x[i] = __expf(x[i] - mx); s += x[i]; }
#pragma unroll
    for (int off = 32; off > 0; off >>= 1) s += __shfl_xor(s, off);
    if (lane == 0) rsum[w] = s;
    __syncthreads();
    s = rsum[0] + rsum[1] + rsum[2] + rsum[3];

    const float inv = 1.f / s;
    f16x8 o;
#pragma unroll
    for (int i = 0; i < 8; ++i) o[i] = (_Float16)(x[i] * inv);
    *(f16x8*)(p + t * 8) = o;
}

// ---------------------------------------------------------------------------
// B=4, Lq=Lk=2048, D=1024.
// q = Xq@Wq+bq ; k = Xk@Wk+bk ; vT = (Xv@Wv+bv)^T (computed directly as NT)
// S = softmax(q k^T / 32) ; out = S @ v
// ---------------------------------------------------------------------------
extern "C" void kernel_launch(void* const* d_in, const int* in_sizes, int n_in,
                              void* d_out, int out_size, void* d_ws, size_t ws_size,
                              hipStream_t stream)
{
    const float* Xq = (const float*)d_in[0];
    const float* Xk = (const float*)d_in[1];
    const float* Xv = (const float*)d_in[2];
    const float* Wq = (const float*)d_in[3];
    const float* bq = (const float*)d_in[4];
    const float* Wk = (const float*)d_in[5];
    const float* bk = (const float*)d_in[6];
    const float* Wv = (const float*)d_in[7];
    const float* bv = (const float*)d_in[8];
    float* out = (float*)d_out;

    const size_t XN = (size_t)8192 * 1024;   // 8,388,608 halfs per X/q/k/vT
    const size_t WN = (size_t)1024 * 1024;

    _Float16* ws  = (_Float16*)d_ws;
    _Float16* Xqh = ws;
    _Float16* Xkh = Xqh + XN;
    _Float16* Xvh = Xkh + XN;
    _Float16* WqT = Xvh + XN;
    _Float16* WkT = WqT + WN;
    _Float16* WvT = WkT + WN;
    _Float16* qh  = WvT + WN;
    _Float16* kh  = qh + XN;
    _Float16* vT  = kh + XN;                 // [1024 x 8192], batch b = cols [b*2048, b*2048+2048)
    _Float16* S   = vT + XN;                 // [4 x 2048 x 2048]

    // 1. convert inputs to f16
    cvt_f32_f16<<<8192, 256, 0, stream>>>((const float4*)Xq, Xqh);
    cvt_f32_f16<<<8192, 256, 0, stream>>>((const float4*)Xk, Xkh);
    cvt_f32_f16<<<8192, 256, 0, stream>>>((const float4*)Xv, Xvh);

    // 2. transpose weights to f16 W^T
    {
        dim3 tb(32, 8), tg(32, 32);
        transpose_w_1024<<<tg, tb, 0, stream>>>(Wq, WqT);
        transpose_w_1024<<<tg, tb, 0, stream>>>(Wk, WkT);
        transpose_w_1024<<<tg, tb, 0, stream>>>(Wv, WvT);
    }

    // 3. projections
    {
        dim3 g(1024 / 128, 8192 / 128, 1);   // q, k: C[8192,1024]
        gemm_nt_f16<1, false><<<g, 256, 0, stream>>>(Xqh, WqT, qh, bq,
            8192, 1024, 1024, 1024, 1024, 1024, 0, 0, 0, 1.f);
        gemm_nt_f16<1, false><<<g, 256, 0, stream>>>(Xkh, WkT, kh, bk,
            8192, 1024, 1024, 1024, 1024, 1024, 0, 0, 0, 1.f);
    }
    {
        dim3 g(8192 / 128, 1024 / 128, 1);   // vT[d][l] = sum_k WvT[d][k] Xv[l][k] + bv[d]
        gemm_nt_f16<2, false><<<g, 256, 0, stream>>>(WvT, Xvh, vT, bv,
            1024, 8192, 1024, 1024, 1024, 8192, 0, 0, 0, 1.f);
    }

    // 4. S = q k^T / 32  (per batch, f16 out)
    {
        dim3 g(2048 / 128, 2048 / 128, 4);
        gemm_nt_f16<0, false><<<g, 256, 0, stream>>>(qh, kh, S, nullptr,
            2048, 2048, 1024, 1024, 1024, 2048,
            (long long)2048 * 1024, (long long)2048 * 1024, (long long)2048 * 2048,
            0.03125f);
    }

    // 5. softmax rows (in place)
    softmax_rows_2048<<<8192, 256, 0, stream>>>(S);

    // 6. out = P @ v  (B operand = vT rows, K = 2048 keys), f32 out
    {
        dim3 g(1024 / 128, 2048 / 128, 4);
        gemm_nt_f16<0, true><<<g, 256, 0, stream>>>(S, vT, out, nullptr,
            2048, 1024, 2048, 2048, 8192, 1024,
            (long long)2048 * 2048, (long long)2048, (long long)2048 * 1024,
            1.f);
    }
}